// Round 7
// baseline (429.641 us; speedup 1.0000x reference)
//
#include <hip/hip_runtime.h>
#include <cstdint>
#include <cstddef>

// ---------- types ----------
typedef __bf16 bf16x8 __attribute__((ext_vector_type(8)));
typedef __bf16 bf16x4 __attribute__((ext_vector_type(4)));
typedef float  f32x4  __attribute__((ext_vector_type(4)));

// async global->LDS, 16B per lane, dest = wave-uniform base + lane*16
__device__ __forceinline__ void gload_lds16(const void* g, void* l) {
    __builtin_amdgcn_global_load_lds(
        (const __attribute__((address_space(1))) void*)g,
        (__attribute__((address_space(3))) void*)l, 16, 0, 0);
}

// ---------- problem constants ----------
// B=2, S=2048, Hdim=2048, NH=16, KV=4, D=128
#define SEQ 2048
#define NH 16
#define NKV 4
#define HD 128

// ---------- fused f32 -> bf16 convert of all 5 inputs (one launch) ----------
__global__ __launch_bounds__(256) void cvt_all(const float* __restrict__ hs,
                                               const float* __restrict__ wq,
                                               const float* __restrict__ wk,
                                               const float* __restrict__ wv,
                                               const float* __restrict__ wo,
                                               __bf16* __restrict__ hB,
                                               __bf16* __restrict__ WqkB,
                                               __bf16* __restrict__ WvB,
                                               __bf16* __restrict__ WoB) {
    int bid = blockIdx.x;
    const float* in; __bf16* out; int base;
    if (bid < 8192)        { in = hs; out = hB;                   base = bid; }
    else if (bid < 12288)  { in = wq; out = WqkB;                 base = bid - 8192; }
    else if (bid < 13312)  { in = wk; out = WqkB + 2048 * 2048;   base = bid - 12288; }
    else if (bid < 14336)  { in = wv; out = WvB;                  base = bid - 13312; }
    else                   { in = wo; out = WoB;                  base = bid - 14336; }
    int i = base * 256 + threadIdx.x;
    float4 v = ((const float4*)in)[i];
    bf16x4 o = { (__bf16)v.x, (__bf16)v.y, (__bf16)v.z, (__bf16)v.w };
    ((bf16x4*)out)[i] = o;
}

// ---------- fused QKV projection GEMM, K=2048, BK=32, DOUBLE-BUFFERED -------
// One barrier per K-iter: stage(t+1) issued right after the barrier, compute(t)
// runs before the next barrier drains those loads -> the vmcnt(0) drain is
// hidden behind ~8 ds_read_b128 + 16 MFMA instead of a bare L2/HBM round-trip.
// y in [0,16):  C = hB @ Wq_head(y)^T  -> RoPE(+scale) -> Qr [B,NH,S,D]
// y in [16,20): C = hB @ Wk_head^T     -> RoPE         -> Kr [B,KV,S,D]
// y in [20,24): C = Wv_rows @ hB^T     -> plain        -> VT [KV*D][B*S]
__global__ __launch_bounds__(256) void qkv_gemm(const __bf16* __restrict__ hB,
                                                const __bf16* __restrict__ Wqk,
                                                const __bf16* __restrict__ Wv,
                                                __bf16* __restrict__ Qr,
                                                __bf16* __restrict__ Kr,
                                                __bf16* __restrict__ VT) {
    __shared__ __align__(16) __bf16 lA[2][4][128][8];  // 2 x 8 KB
    __shared__ __align__(16) __bf16 lB[2][4][128][8];  // 2 x 8 KB
    const int tid = threadIdx.x;
    const int wave = tid >> 6, lane = tid & 63;
    const int quad = lane >> 4, l16 = lane & 15;
    const int x = blockIdx.x, y = blockIdx.y;
    const bool isVT = (y >= 20);

    const __bf16* A = isVT ? Wv : hB;
    const __bf16* W = isVT ? hB : Wqk;
    const int bm = isVT ? (y - 20) * 128 : x * 128;
    const int bn = isVT ? x * 128 : y * 128;
    const int wm = (wave & 1) * 64, wn2 = (wave >> 1) * 32;

    // per-wave staging constants: chunks c = wave*2 + t, t in {0,1}
    const int c0 = wave * 2, c1 = wave * 2 + 1;
    const int qs0 = c0 >> 1, ms0 = ((c0 & 1) << 6) + lane;
    const int qs1 = c1 >> 1, ms1 = ((c1 & 1) << 6) + lane;
    const __bf16* Arow0 = A + (size_t)(bm + ms0) * 2048 + qs0 * 8;
    const __bf16* Arow1 = A + (size_t)(bm + ms1) * 2048 + qs1 * 8;
    const __bf16* Wrow0 = W + (size_t)(bn + ms0) * 2048 + qs0 * 8;
    const __bf16* Wrow1 = W + (size_t)(bn + ms1) * 2048 + qs1 * 8;

    f32x4 acc[4][4] = {};

    // prologue: stage tile 0 into buffer 0
    {
        char* a = (char*)&lA[0][0][0][0];
        char* b = (char*)&lB[0][0][0][0];
        gload_lds16(Arow0, a + c0 * 1024);
        gload_lds16(Arow1, a + c1 * 1024);
        gload_lds16(Wrow0, b + c0 * 1024);
        gload_lds16(Wrow1, b + c1 * 1024);
    }

    for (int t = 0; t < 64; ++t) {
        const int p = t & 1;
        __syncthreads();  // drains stage-t loads; fences reads of buf[p^1]
        if (t < 63) {
            const int k1 = (t + 1) * 32;
            char* a = (char*)&lA[p ^ 1][0][0][0];
            char* b = (char*)&lB[p ^ 1][0][0][0];
            gload_lds16(Arow0 + k1, a + c0 * 1024);
            gload_lds16(Arow1 + k1, a + c1 * 1024);
            gload_lds16(Wrow0 + k1, b + c0 * 1024);
            gload_lds16(Wrow1 + k1, b + c1 * 1024);
        }
        bf16x8 af[4], bfr[4];
#pragma unroll
        for (int i = 0; i < 4; ++i)
            af[i] = *(const bf16x8*)&lA[p][quad][wm + i * 16 + l16][0];
#pragma unroll
        for (int j = 0; j < 4; ++j)
            bfr[j] = *(const bf16x8*)&lB[p][quad][wn2 + (j & 1) * 16 + (j >> 1) * 64 + l16][0];
#pragma unroll
        for (int i = 0; i < 4; ++i)
#pragma unroll
            for (int j = 0; j < 4; ++j)
                acc[i][j] = __builtin_amdgcn_mfma_f32_16x16x32_bf16(
                    af[i], bfr[j], acc[i][j], 0, 0, 0);
    }

    if (isVT) {
#pragma unroll
        for (int i = 0; i < 4; ++i)
#pragma unroll
            for (int j = 0; j < 4; ++j) {
                int row = bm + wm + i * 16 + quad * 4;
                int col = bn + wn2 + (j & 1) * 16 + (j >> 1) * 64 + l16;
#pragma unroll
                for (int r = 0; r < 4; ++r)
                    VT[(size_t)(row + r) * 4096 + col] = (__bf16)acc[i][j][r];
            }
    } else {
        const bool isQ = (y < 16);
        __bf16* outp = isQ ? Qr : Kr;
        const float sc = isQ ? 0.08838834764831845f : 1.0f;  // folded 1/sqrt(D)
        const int hh = isQ ? y : (y - 16);
        const int nh = isQ ? NH : NKV;
#pragma unroll
        for (int j2 = 0; j2 < 2; ++j2) {
            int d = wn2 + j2 * 16 + l16;  // 0..63
            float inv = exp2f(-(float)d * 0.2076205059304601f);  // log2(1e4)/64
#pragma unroll
            for (int i = 0; i < 4; ++i)
#pragma unroll
                for (int r = 0; r < 4; ++r) {
                    int m = bm + wm + i * 16 + quad * 4 + r;
                    int s = m & (SEQ - 1), b = m >> 11;
                    float f = (float)s * inv;
                    float c = __cosf(f) * sc, sn = __sinf(f) * sc;
                    float x1 = acc[i][j2][r], x2 = acc[i][j2 + 2][r];
                    size_t rb = ((size_t)(b * nh + hh) * SEQ + s) * HD;
                    outp[rb + d]      = (__bf16)(x1 * c - x2 * sn);
                    outp[rb + d + 64] = (__bf16)(x2 * c + x1 * sn);
                }
        }
    }
}

// ---------- Wo GEMM, BK=32, DOUBLE-BUFFERED: C = A @ W^T, f32 out ----------
__global__ __launch_bounds__(256) void gemm_bt_f32(const __bf16* __restrict__ A,
                                                   const __bf16* __restrict__ W,
                                                   float* __restrict__ C,
                                                   int N, int K) {
    __shared__ __align__(16) __bf16 lA[2][4][128][8];
    __shared__ __align__(16) __bf16 lB[2][4][128][8];
    const int tid = threadIdx.x;
    const int wave = tid >> 6, lane = tid & 63;
    const int quad = lane >> 4, l16 = lane & 15;
    const int bm = blockIdx.x * 128, bn = blockIdx.y * 128;
    const int wm = (wave & 1) * 64, wn = (wave >> 1) * 64;

    const int c0 = wave * 2, c1 = wave * 2 + 1;
    const int qs0 = c0 >> 1, ms0 = ((c0 & 1) << 6) + lane;
    const int qs1 = c1 >> 1, ms1 = ((c1 & 1) << 6) + lane;
    const __bf16* Arow0 = A + (size_t)(bm + ms0) * K + qs0 * 8;
    const __bf16* Arow1 = A + (size_t)(bm + ms1) * K + qs1 * 8;
    const __bf16* Wrow0 = W + (size_t)(bn + ms0) * K + qs0 * 8;
    const __bf16* Wrow1 = W + (size_t)(bn + ms1) * K + qs1 * 8;

    f32x4 acc[4][4] = {};
    const int T = K >> 5;

    {
        char* a = (char*)&lA[0][0][0][0];
        char* b = (char*)&lB[0][0][0][0];
        gload_lds16(Arow0, a + c0 * 1024);
        gload_lds16(Arow1, a + c1 * 1024);
        gload_lds16(Wrow0, b + c0 * 1024);
        gload_lds16(Wrow1, b + c1 * 1024);
    }

    for (int t = 0; t < T; ++t) {
        const int p = t & 1;
        __syncthreads();
        if (t < T - 1) {
            const int k1 = (t + 1) * 32;
            char* a = (char*)&lA[p ^ 1][0][0][0];
            char* b = (char*)&lB[p ^ 1][0][0][0];
            gload_lds16(Arow0 + k1, a + c0 * 1024);
            gload_lds16(Arow1 + k1, a + c1 * 1024);
            gload_lds16(Wrow0 + k1, b + c0 * 1024);
            gload_lds16(Wrow1 + k1, b + c1 * 1024);
        }
        bf16x8 af[4], bfr[4];
#pragma unroll
        for (int i = 0; i < 4; ++i)
            af[i] = *(const bf16x8*)&lA[p][quad][wm + i * 16 + l16][0];
#pragma unroll
        for (int j = 0; j < 4; ++j)
            bfr[j] = *(const bf16x8*)&lB[p][quad][wn + j * 16 + l16][0];
#pragma unroll
        for (int i = 0; i < 4; ++i)
#pragma unroll
            for (int j = 0; j < 4; ++j)
                acc[i][j] = __builtin_amdgcn_mfma_f32_16x16x32_bf16(
                    af[i], bfr[j], acc[i][j], 0, 0, 0);
    }

#pragma unroll
    for (int i = 0; i < 4; ++i)
#pragma unroll
        for (int j = 0; j < 4; ++j) {
            int row = bm + wm + i * 16 + quad * 4;
            int col = bn + wn + j * 16 + l16;
#pragma unroll
            for (int r = 0; r < 4; ++r)
                C[(size_t)(row + r) * N + col] = acc[i][j][r];
        }
}

// ---------- flash attention, split-K x2, 32 q/wave ----------
// grid (S/128, NH, B*2): z = b*2+ks; block covers q-tile 128, kpos half-range.
// No-max safe-exp softmax => split-K partials are directly additive:
// AOp[ks] = unnormalized O^T (bf16), lsum[ks][b][h][q] (f32).
__global__ __launch_bounds__(256) void attn_kernel(const __bf16* __restrict__ Q,
                                                   const __bf16* __restrict__ Kr,
                                                   const __bf16* __restrict__ VT,
                                                   __bf16* __restrict__ AOp0,
                                                   __bf16* __restrict__ AOp1,
                                                   float* __restrict__ lsum) {
    __shared__ __align__(16) __bf16 kt[16][64][8];  // [d-slab][kpos][8]
    __shared__ __align__(16) __bf16 vt[8][128][8];  // [kpos-slab][d][8]
    __shared__ __align__(16) __bf16 Pb[4][32][72];  // [wave][q][kpos + pad8]

    const int tid = threadIdx.x;
    const int wave = tid >> 6, lane = tid & 63;
    const int quad = lane >> 4, l16 = lane & 15;
    const int h = blockIdx.y, z = blockIdx.z;
    const int b = z >> 1, ks = z & 1, kv = h >> 2;
    const int qbase = blockIdx.x * 128 + wave * 32;

    bf16x8 qf[2][4];
#pragma unroll
    for (int qs = 0; qs < 2; ++qs) {
        const __bf16* Qp =
            Q + ((size_t)(b * NH + h) * SEQ + qbase + qs * 16 + l16) * HD + quad * 8;
#pragma unroll
        for (int kq = 0; kq < 4; ++kq) qf[qs][kq] = *(const bf16x8*)(Qp + kq * 32);
    }

    const __bf16* Kp = Kr + (size_t)(b * NKV + kv) * SEQ * HD;
    const __bf16* Vp = VT + (size_t)(kv * HD) * (2 * SEQ) + b * SEQ;

    f32x4 oacc[2][8] = {};
    float lpart[2] = {0.f, 0.f};

    for (int k0 = ks * 1024; k0 < ks * 1024 + 1024; k0 += 64) {
        __syncthreads();
#pragma unroll
        for (int t = 0; t < 4; ++t) {
            int c = wave * 4 + t;
            gload_lds16(Kp + (size_t)(k0 + lane) * HD + c * 8,
                        (char*)&kt[0][0][0] + c * 1024);
            gload_lds16(Vp + (size_t)(((c & 1) << 6) + lane) * (2 * SEQ) + k0 + (c >> 1) * 8,
                        (char*)&vt[0][0][0] + c * 1024);
        }
        __syncthreads();

        // S^T tile: ka shared by both q-sets (2 MFMA per ds_read)
#pragma unroll
        for (int mt = 0; mt < 4; ++mt) {
            f32x4 s0 = {0.f, 0.f, 0.f, 0.f}, s1 = {0.f, 0.f, 0.f, 0.f};
#pragma unroll
            for (int kq = 0; kq < 4; ++kq) {
                bf16x8 ka = *(const bf16x8*)&kt[kq * 4 + quad][mt * 16 + l16][0];
                s0 = __builtin_amdgcn_mfma_f32_16x16x32_bf16(ka, qf[0][kq], s0, 0, 0, 0);
                s1 = __builtin_amdgcn_mfma_f32_16x16x32_bf16(ka, qf[1][kq], s1, 0, 0, 0);
            }
            bf16x4 pk0, pk1;
#pragma unroll
            for (int r = 0; r < 4; ++r) {
                float p0 = __expf(s0[r]);
                float p1 = __expf(s1[r]);
                lpart[0] += p0; lpart[1] += p1;
                pk0[r] = (__bf16)p0; pk1[r] = (__bf16)p1;
            }
            *(bf16x4*)&Pb[wave][l16][mt * 16 + quad * 4] = pk0;
            *(bf16x4*)&Pb[wave][16 + l16][mt * 16 + quad * 4] = pk1;
        }

        // O^T += VT_tile @ P^T; va shared by both q-sets
#pragma unroll
        for (int kk = 0; kk < 2; ++kk) {
            bf16x8 pb0 = *(const bf16x8*)&Pb[wave][l16][kk * 32 + quad * 8];
            bf16x8 pb1 = *(const bf16x8*)&Pb[wave][16 + l16][kk * 32 + quad * 8];
#pragma unroll
            for (int mt = 0; mt < 8; ++mt) {
                bf16x8 va = *(const bf16x8*)&vt[kk * 4 + quad][mt * 16 + l16][0];
                oacc[0][mt] = __builtin_amdgcn_mfma_f32_16x16x32_bf16(
                    va, pb0, oacc[0][mt], 0, 0, 0);
                oacc[1][mt] = __builtin_amdgcn_mfma_f32_16x16x32_bf16(
                    va, pb1, oacc[1][mt], 0, 0, 0);
            }
        }
    }

    // epilogue: unnormalized partial O^T (bf16) + l partials (f32)
    __bf16* AOp = ks ? AOp1 : AOp0;
#pragma unroll
    for (int qs = 0; qs < 2; ++qs) {
        lpart[qs] += __shfl_xor(lpart[qs], 16);
        lpart[qs] += __shfl_xor(lpart[qs], 32);
        int q = qbase + qs * 16 + l16;
#pragma unroll
        for (int mt = 0; mt < 8; ++mt) {
            bf16x4 ov;
#pragma unroll
            for (int r = 0; r < 4; ++r) ov[r] = (__bf16)oacc[qs][mt][r];
            *(bf16x4*)(AOp + ((size_t)(b * SEQ + q)) * (NH * HD) + h * HD +
                       mt * 16 + quad * 4) = ov;
        }
        if (quad == 0)
            lsum[((size_t)(ks * 2 + b) * NH + h) * SEQ + q] = lpart[qs];
    }
}

// ---------- combine split-K partials: AO = (AOp0 + AOp1) / (l0 + l1) ----------
__global__ __launch_bounds__(256) void combine_kernel(const __bf16* __restrict__ AOp0,
                                                      const __bf16* __restrict__ AOp1,
                                                      const float* __restrict__ lsum,
                                                      __bf16* __restrict__ AO) {
    int i = blockIdx.x * 256 + threadIdx.x;  // 1,048,576 threads, 8 elems each
    int row = i >> 8;                        // (b*2048+q), 0..4095
    int colIdx = i & 255;                    // *8 = col in [0,2048)
    int b = row >> 11, q = row & 2047, hh = colIdx >> 4;
    float l0 = lsum[((size_t)b * NH + hh) * SEQ + q];
    float l1 = lsum[((size_t)(2 + b) * NH + hh) * SEQ + q];
    float inv = 1.f / (l0 + l1);
    bf16x8 a0 = ((const bf16x8*)AOp0)[i];
    bf16x8 a1 = ((const bf16x8*)AOp1)[i];
    bf16x8 o;
#pragma unroll
    for (int j = 0; j < 8; ++j) o[j] = (__bf16)(((float)a0[j] + (float)a1[j]) * inv);
    ((bf16x8*)AO)[i] = o;
}

// ---------- launch ----------
extern "C" void kernel_launch(void* const* d_in, const int* in_sizes, int n_in,
                              void* d_out, int out_size, void* d_ws, size_t ws_size,
                              hipStream_t stream) {
    const float* hs = (const float*)d_in[0];
    const float* Wq = (const float*)d_in[1];
    const float* Wk = (const float*)d_in[2];
    const float* Wv = (const float*)d_in[3];
    const float* Wo = (const float*)d_in[4];
    float* out = (float*)d_out;
    char* ws = (char*)d_ws;

    // workspace layout (bytes), total 67.63 MB:
    //   Qr   [0,      16.78M)  [B][NH][S][D]     -> AO alias after attn
    //   Kr   [16.78M, 20.97M)  [B][KV][S][D]
    //   VT   [20.97M, 25.17M)  [KV*D][B*S]
    //   WoB  [25.17M, 33.56M)  [2048][2048]
    //   hB   [33.56M, 50.33M)  (dead after qkv)  -> AOp0 alias
    //   WqkB [50.33M, 60.82M)  (dead after qkv)  -> AOp1 alias [50.33M,67.11M)
    //   WvB  [60.82M, 62.91M)  (dead after qkv, inside AOp1 region)
    //   lsum [67.11M, 67.63M)  f32 [2ks][B][NH][S]
    __bf16* Qr   = (__bf16*)(ws + 0);
    __bf16* Kr   = (__bf16*)(ws + 16777216);
    __bf16* VT   = (__bf16*)(ws + 20971520);
    __bf16* WoB  = (__bf16*)(ws + 25165824);
    __bf16* hB   = (__bf16*)(ws + 33554432);
    __bf16* WqkB = (__bf16*)(ws + 50331648);
    __bf16* WvB  = (__bf16*)(ws + 60817408);
    __bf16* AOp0 = (__bf16*)(ws + 33554432);  // alias hB
    __bf16* AOp1 = (__bf16*)(ws + 50331648);  // alias WqkB+WvB
    float*  lsum = (float*) (ws + 67108864);
    __bf16* AO   = (__bf16*)(ws + 0);         // alias Qr

    // 1) one fused convert launch
    cvt_all<<<18432, 256, 0, stream>>>(hs, Wq, Wk, Wv, Wo, hB, WqkB, WvB, WoB);

    // 2) fused Q/K/V projection + RoPE + transposes (BK=32, double-buffered)
    qkv_gemm<<<dim3(32, 24), 256, 0, stream>>>(hB, WqkB, WvB, Qr, Kr, VT);

    // 3) attention (split-K x2: z = b*2 + ks)
    attn_kernel<<<dim3(16, 16, 4), 256, 0, stream>>>(Qr, Kr, VT, AOp0, AOp1, lsum);

    // 4) combine partials
    combine_kernel<<<4096, 256, 0, stream>>>(AOp0, AOp1, lsum, AO);

    // 5) output projection (f32 out, BK=32, double-buffered)
    gemm_bt_f32<<<dim3(32, 16), 256, 0, stream>>>(AO, WoB, out, 2048, 2048);
}